// Round 5
// baseline (168.097 us; speedup 1.0000x reference)
//
#include <hip/hip_runtime.h>
#include <math.h>

#define B_    4
#define C_    19
#define H_    320
#define W_    320
#define HW_   (H_*W_)
#define CHW_  (C_*HW_)
#define NPIX_ (B_*HW_)
#define NEPS_ 256
#define BIGI_ (1<<20)
#define INF_  0x3fffffff
#define IGN_  255

// Compile-time exact replica of the reference eps chain: e0=1e-5f, e_{k+1}=e_k*1.2f
struct EpsTab { float v[NEPS_]; };
static constexpr EpsTab make_eps() {
  EpsTab t{}; float e = 1e-5f;
  for (int k = 0; k < NEPS_; ++k) { t.v[k] = e; e = e * 1.2f; }
  return t;
}
__device__ __constant__ EpsTab EPS = make_eps();

// ---------------- reduction helper (nw full waves) ---------------------------
__device__ __forceinline__ void block_reduce_add_w(float v, float* out, int nw) {
  #pragma unroll
  for (int o = 32; o > 0; o >>= 1) v += __shfl_down(v, o);
  __shared__ float shr[8];
  int lane = threadIdx.x & 63, wid = threadIdx.x >> 6;
  if (lane == 0) shr[wid] = v;
  __syncthreads();
  if (threadIdx.x == 0) {
    float s = 0.f;
    for (int w = 0; w < nw; ++w) s += shr[w];
    atomicAdd(out, s);
  }
}

__device__ __forceinline__ int eps_bin(float kl, const float* et) {
  // #{k : e_k < kl}, log2 guess + exact correction (identical compares to ref)
  if (!(kl > 1e-5f)) return 0;
  int g = (int)((__log2f(kl) + 16.6096404f) * 3.8017840f);
  g = min(max(g, 0), NEPS_ - 1);
  while (g < NEPS_ && et[g] < kl) ++g;
  while (g > 0 && !(et[g - 1] < kl)) --g;
  return g;
}

// ---------------- K1: row distance transform + workspace init ---------------
// Writes R TRANSPOSED (R_t[b][j][i]) so k_coldt's column loads are coalesced.
// Block 0 also zeroes hist/out (stream order makes them visible to k_soft).
__global__ __launch_bounds__(320) void k_rowdt(const int* __restrict__ tgt, int* __restrict__ Rt,
                                               int* __restrict__ hist, float* __restrict__ out) {
  int bid = blockIdx.x;                  // b*H_ + i
  int b = bid / H_, i = bid - b * H_;
  int j = threadIdx.x, lane = j & 63, wv = j >> 6;
  if (bid == 0) {
    if (j < 257) hist[j] = 0;
    if (j == 319) out[0] = 0.f;
  }
  bool hd = (i < H_ - 1);
  const int* trow = tgt + b * HW_ + i * W_;
  int t0 = trow[j];
  int t1 = hd ? trow[W_ + j] : t0;
  int t0r = (j < W_ - 1) ? trow[j + 1] : t0;
  bool bnd = (t0 == IGN_) || (t1 != t0) || (t0r != t0);
  int s = bnd ? 0 : BIGI_;
  int a = s - j, c = s + j;
  #pragma unroll
  for (int o = 1; o < 64; o <<= 1) {
    int v = __shfl_up(a, o);
    if (lane >= o) a = min(a, v);
    int w = __shfl_down(c, o);
    if (lane + o < 64) c = min(c, w);
  }
  __shared__ int wa[5], wc[5];
  if (lane == 63) wa[wv] = a;
  if (lane == 0)  wc[wv] = c;
  __syncthreads();
  #pragma unroll
  for (int w = 0; w < 5; ++w) {
    if (w < wv) a = min(a, wa[w]);
    if (w > wv) c = min(c, wc[w]);
  }
  Rt[(b * W_ + j) * H_ + i] = min(a + j, c - j);   // transposed store
}

// ---------------- K0: LDS-tiled softmax/KL/nll/hist -------------------------
// 64x4-pixel tile per block (+1 col / +1 row halo) staged once into LDS:
// 65*5*19 fp32 = 24.7 KB. Unique-ish global traffic 1.27x (37 MB total) vs the
// previous per-thread scheme's ~78 MB, and exps drop 57/px -> ~21/px.
// Phase 1: every thread computes its own se/E from LDS (c-ascending, same
// __expf order as all prior rounds); 69 threads double-duty the halo pixels'
// se. Phase 2: neighbor KL dots read neighbor logits from LDS and neighbor
// exp-sums from ses[][] -- bitwise identical to the neighbor's own stats
// (same accumulation), the invariant that has held absmax=0.0 since round 1.
__global__ __launch_bounds__(256) void k_soft(const float* __restrict__ sl, const int* __restrict__ tgt,
                                              float* __restrict__ logZ, float* __restrict__ S,
                                              float* __restrict__ kl_map, int* __restrict__ hist,
                                              float* __restrict__ out) {
  int tid = threadIdx.x;
  int b = blockIdx.z;
  int i0 = blockIdx.y * 4, j0 = blockIdx.x * 64;
  int li = tid >> 6, lj = tid & 63;
  int gi = i0 + li, gj = j0 + lj;
  __shared__ float xs[C_][5][65];        // [ch][row][col], col stride-1
  __shared__ float ses[5][65];           // per-pixel exp-sums (incl. halo)
  __shared__ float et[NEPS_];
  __shared__ int sh[257];
  et[tid] = EPS.v[tid];
  sh[tid] = 0;
  if (tid == 0) sh[256] = 0;
  const float* gb = sl + (size_t)b * CHW_;
  #pragma unroll
  for (int c = 0; c < C_; ++c) {
    for (int sub = tid; sub < 325; sub += 256) {
      int r = sub / 65, col = sub - r * 65;
      int ii = i0 + r, jj = j0 + col;
      xs[c][r][col] = (ii < H_ && jj < W_) ? gb[c * HW_ + ii * W_ + jj] : 0.f;
    }
  }
  int t0 = tgt[b * HW_ + gi * W_ + gj];
  __syncthreads();
  // ---- phase 1: own softmax stats (exp values kept in registers) ----
  float eo[C_];
  float se = 0.f, E = 0.f, xt = 0.f;
  #pragma unroll
  for (int c = 0; c < C_; ++c) {
    float x = xs[c][li][lj];
    float e = __expf(x);
    eo[c] = e; se += e; E += e * x;
    if (c == t0) xt = x;
  }
  ses[li][lj] = se;
  // halo pixels: threads 0..64 -> (row 4, col tid); 65..68 -> (row tid-65, col 64)
  if (tid < 69) {
    int hrr = (tid < 65) ? 4 : (tid - 65);
    int hcc = (tid < 65) ? tid : 64;
    float seh = 0.f;
    #pragma unroll
    for (int c = 0; c < C_; ++c) seh += __expf(xs[c][hrr][hcc]);
    ses[hrr][hcc] = seh;
  }
  __syncthreads();
  // ---- phase 2: neighbor KL from LDS ----
  bool hd = (gi < H_ - 1), hr = (gj < W_ - 1);
  float dD = 0.f, dR = 0.f;
  #pragma unroll
  for (int c = 0; c < C_; ++c) {
    dD += eo[c] * xs[c][li + 1][lj];
    dR += eo[c] * xs[c][li][lj + 1];
  }
  float lz = __logf(se);
  float Sv = E / se - lz;
  float nll = (t0 != IGN_) ? (lz - xt) : 0.f;
  float kl = hd ? (Sv - dD / se + __logf(ses[li + 1][lj])) : 0.f;
  if (hr) kl += Sv - dR / se + __logf(ses[li][lj + 1]);
  int gp = b * HW_ + gi * W_ + gj;
  logZ[gp] = lz; S[gp] = Sv; kl_map[gp] = kl;
  atomicAdd(&sh[eps_bin(kl, et)], 1);
  __syncthreads();
  if (sh[tid]) atomicAdd(&hist[tid], sh[tid]);
  if (tid == 0 && sh[256]) atomicAdd(&hist[256], sh[256]);
  block_reduce_add_w(nll, out, 4);
}

// ---------------- K2: column combine + (block 0) eps selection --------------
// Reads the TRANSPOSED R: lev[0] load fully coalesced.
__global__ __launch_bounds__(H_) void k_coldt(const int* __restrict__ Rt, int* __restrict__ dist,
                                              const int* __restrict__ hist, float* __restrict__ eps_sel) {
  int b = blockIdx.x / W_, j = blockIdx.x % W_, tid = threadIdx.x;
  __shared__ int lev[9][H_];
  lev[0][tid] = Rt[(b * W_ + j) * H_ + tid];
  int Ri = lev[0][tid];
  for (int l = 1; l <= 8; ++l) {
    int half = 1 << (l - 1);
    __syncthreads();
    int other = (tid + half < H_) ? lev[l - 1][tid + half] : INF_;
    lev[l][tid] = min(lev[l - 1][tid], other);
  }
  __syncthreads();
  int i0 = tid;
  auto feas = [&](int dd) -> bool {
    int lo = max(0, i0 - dd), hi = min(H_ - 1, i0 + dd);
    int len = hi - lo + 1;
    int l = 31 - __clz(len);
    int m = min(lev[l][lo], lev[l][hi - (1 << l) + 1]);
    return m <= dd;
  };
  int d;
  int hi = min(Ri, 512);                 // d <= R[i0]
  if (!feas(hi)) d = B_ + 1 + H_ + W_;   // no seed in image
  else {
    int lo = 0;
    while (lo < hi) { int mid = (lo + hi) >> 1; if (feas(mid)) hi = mid; else lo = mid + 1; }
    d = lo;
  }
  dist[(b * H_ + i0) * W_ + j] = d;
  // block 0: eps via suffix scan of hist (bins 1..256)
  if (blockIdx.x == 0) {
    __shared__ int g[256];
    __shared__ int bestk;
    if (tid < 256) g[tid] = hist[tid + 1];
    if (tid == 0) bestk = NEPS_ - 1;
    __syncthreads();
    #pragma unroll
    for (int ofs = 1; ofs < 256; ofs <<= 1) {
      int v = 0;
      if (tid < 256) v = g[tid] + ((tid + ofs < 256) ? g[tid + ofs] : 0);
      __syncthreads();
      if (tid < 256) g[tid] = v;
      __syncthreads();
    }
    if (tid < 256 && g[tid] <= 5120) atomicMin(&bestk, tid);
    __syncthreads();
    if (tid == 0) eps_sel[0] = EPS.v[bestk];
  }
}

// ---------------- K3: mask+direction+dterm + in-block sparse CE -------------
__global__ __launch_bounds__(256) void k_maskce(const float* __restrict__ sl, const float* __restrict__ logZ,
                                                const float* __restrict__ S, const float* __restrict__ kl_map,
                                                const int* __restrict__ dist, const float* __restrict__ eps_sel,
                                                float* __restrict__ out) {
  const int nx9[9] = {1,-1,0,0,-1,1,-1,1,0};
  const int ny9[9] = {0,0,-1,1,1,1,-1,-1,0};
  int tid = threadIdx.x;
  int b = blockIdx.z;
  int i0 = blockIdx.y * 16, j0 = blockIdx.x * 16;
  float eps = eps_sel[0];
  __shared__ float kt[18][19];
  __shared__ int   dt_[18][19];
  for (int e = tid; e < 324; e += 256) {
    int r = e / 18, cc = e - r * 18;
    int gi = i0 - 1 + r, gj = j0 - 1 + cc;
    bool in = (gi >= 0 && gi < H_ && gj >= 0 && gj < W_);
    int gidx = (b * H_ + gi) * W_ + gj;
    kt[r][cc]  = in ? kl_map[gidx] : -1e30f;
    dt_[r][cc] = in ? dist[gidx] : 100000;
  }
  __syncthreads();
  int li = tid >> 4, lj = tid & 15;
  bool mask = false;
  #pragma unroll
  for (int dr = 0; dr < 3; ++dr)
    #pragma unroll
    for (int dc = 0; dc < 3; ++dc)
      mask |= (kt[li + dr][lj + dc] > eps);
  int best = INF_, dir = 0;
  #pragma unroll
  for (int k = 0; k < 9; ++k) {
    int r = dt_[li + 1 + nx9[k]][lj + 1 + ny9[k]];
    if (r < best) { best = r; dir = k; }
  }
  bool valid = mask && (dir != 8);
  float acc = valid ? fminf((float)dt_[li + 1][lj + 1], 20.f) * (1.f / 20.f) : 0.f;
  // compact valid pixels into LDS list
  __shared__ int list_[256];
  __shared__ int woff[4];
  __shared__ int tot_s;
  int lane = tid & 63, wid = tid >> 6;
  unsigned long long vote = __ballot(valid);
  if (lane == 0) woff[wid] = __popcll(vote);
  __syncthreads();
  if (tid == 0) {
    int c0 = woff[0], c1 = woff[1], c2 = woff[2], c3 = woff[3];
    tot_s = c0 + c1 + c2 + c3;
    woff[0] = 0; woff[1] = c0; woff[2] = c0 + c1; woff[3] = c0 + c1 + c2;
  }
  __syncthreads();
  if (valid)
    list_[woff[wid] + __popcll(vote & ((1ULL << lane) - 1ULL))] = tid | (min(dir, 7) << 8);
  __syncthreads();
  int cnt = tot_s;
  const float* bse = sl + (size_t)b * CHW_;
  // CE: 8 lanes per entry (lane k = neighbor k)
  for (int base0 = 0; base0 < cnt; base0 += 32) {
    int e = base0 + (tid >> 3), k = tid & 7;
    float ce = 0.f;
    if (e < cnt) {
      int w = list_[e];
      int label = w >> 8, lpos = w & 255;
      int i = i0 + (lpos >> 4), j = j0 + (lpos & 15);
      int pix = i * W_ + j;
      float lzc = logZ[b * HW_ + pix];
      int ic = min(max(i + nx9[k], 0), H_ - 1);
      int jc = min(max(j + ny9[k], 0), W_ - 1);
      int npx = ic * W_ + jc;
      float lzn = logZ[b * HW_ + npx], Sn = S[b * HW_ + npx];
      float dot = 0.f;
      #pragma unroll
      for (int c = 0; c < C_; ++c)
        dot += __expf(bse[c * HW_ + npx] - lzn) * bse[c * HW_ + pix];
      float kv = Sn - dot + lzc;
      float kmax = kv;
      #pragma unroll
      for (int o = 1; o < 8; o <<= 1) kmax = fmaxf(kmax, __shfl_xor(kmax, o));
      float ssum = __expf(kv - kmax);
      #pragma unroll
      for (int o = 1; o < 8; o <<= 1) ssum += __shfl_xor(ssum, o);
      float kll = __shfl(kv, (lane & ~7) | label);
      if (k == 0) ce = kmax + __logf(ssum) - kll;
    }
    acc += ce;
  }
  block_reduce_add_w(acc, out, 4);
}

// ---------------- launch -----------------------------------------------------
extern "C" void kernel_launch(void* const* d_in, const int* in_sizes, int n_in,
                              void* d_out, int out_size, void* d_ws, size_t ws_size,
                              hipStream_t stream) {
  const float* sl  = (const float*)d_in[0];
  const int*   tgt = (const int*)d_in[1];
  float* out = (float*)d_out;

  int*   hist    = (int*)d_ws;                 // 257 ints (zeroed by k_rowdt)
  float* eps_sel = (float*)d_ws + 320;
  float* logZ    = (float*)d_ws + 512;
  float* S       = logZ + NPIX_;
  float* kl_map  = S + NPIX_;
  int*   dist    = (int*)(kl_map + NPIX_);
  int*   Rt      = dist + NPIX_;

  k_rowdt<<<B_ * H_, W_, 0, stream>>>(tgt, Rt, hist, out);
  k_soft<<<dim3(W_ / 64, H_ / 4, B_), 256, 0, stream>>>(sl, tgt, logZ, S, kl_map, hist, out);
  k_coldt<<<B_ * W_, H_, 0, stream>>>(Rt, dist, hist, eps_sel);
  k_maskce<<<dim3(W_ / 16, H_ / 16, B_), 256, 0, stream>>>(sl, logZ, S, kl_map, dist, eps_sel, out);
}

// Round 6
// 139.165 us; speedup vs baseline: 1.2079x; 1.2079x over previous
//
#include <hip/hip_runtime.h>
#include <math.h>

#define B_    4
#define C_    19
#define H_    320
#define W_    320
#define HW_   (H_*W_)
#define CHW_  (C_*HW_)
#define NPIX_ (B_*HW_)
#define NEPS_ 256
#define BIGI_ (1<<20)
#define INF_  0x3fffffff
#define IGN_  255

// Compile-time exact replica of the reference eps chain: e0=1e-5f, e_{k+1}=e_k*1.2f
struct EpsTab { float v[NEPS_]; };
static constexpr EpsTab make_eps() {
  EpsTab t{}; float e = 1e-5f;
  for (int k = 0; k < NEPS_; ++k) { t.v[k] = e; e = e * 1.2f; }
  return t;
}
__device__ __constant__ EpsTab EPS = make_eps();

// ---------------- reduction helper (nw full waves) ---------------------------
__device__ __forceinline__ void block_reduce_add_w(float v, float* out, int nw) {
  #pragma unroll
  for (int o = 32; o > 0; o >>= 1) v += __shfl_down(v, o);
  __shared__ float shr[8];
  int lane = threadIdx.x & 63, wid = threadIdx.x >> 6;
  if (lane == 0) shr[wid] = v;
  __syncthreads();
  if (threadIdx.x == 0) {
    float s = 0.f;
    for (int w = 0; w < nw; ++w) s += shr[w];
    atomicAdd(out, s);
  }
}

__device__ __forceinline__ int eps_bin(float kl, const float* et) {
  // #{k : e_k < kl}, log2 guess + exact correction (identical compares to ref)
  if (!(kl > 1e-5f)) return 0;
  int g = (int)((__log2f(kl) + 16.6096404f) * 3.8017840f);
  g = min(max(g, 0), NEPS_ - 1);
  while (g < NEPS_ && et[g] < kl) ++g;
  while (g > 0 && !(et[g - 1] < kl)) --g;
  return g;
}

// ---------------- K1: row distance transform + workspace init ---------------
// Writes R TRANSPOSED (R_t[b][j][i]) so k_coldt's column loads are coalesced.
// Block 0 also zeroes hist/out (stream order makes them visible to k_soft).
__global__ __launch_bounds__(320) void k_rowdt(const int* __restrict__ tgt, int* __restrict__ Rt,
                                               int* __restrict__ hist, float* __restrict__ out) {
  int bid = blockIdx.x;                  // b*H_ + i
  int b = bid / H_, i = bid - b * H_;
  int j = threadIdx.x, lane = j & 63, wv = j >> 6;
  if (bid == 0) {
    if (j < 257) hist[j] = 0;
    if (j == 319) out[0] = 0.f;
  }
  bool hd = (i < H_ - 1);
  const int* trow = tgt + b * HW_ + i * W_;
  int t0 = trow[j];
  int t1 = hd ? trow[W_ + j] : t0;
  int t0r = (j < W_ - 1) ? trow[j + 1] : t0;
  bool bnd = (t0 == IGN_) || (t1 != t0) || (t0r != t0);
  int s = bnd ? 0 : BIGI_;
  int a = s - j, c = s + j;
  #pragma unroll
  for (int o = 1; o < 64; o <<= 1) {
    int v = __shfl_up(a, o);
    if (lane >= o) a = min(a, v);
    int w = __shfl_down(c, o);
    if (lane + o < 64) c = min(c, w);
  }
  __shared__ int wa[5], wc[5];
  if (lane == 63) wa[wv] = a;
  if (lane == 0)  wc[wv] = c;
  __syncthreads();
  #pragma unroll
  for (int w = 0; w < 5; ++w) {
    if (w < wv) a = min(a, wa[w]);
    if (w > wv) c = min(c, wc[w]);
  }
  Rt[(b * W_ + j) * H_ + i] = min(a + j, c - j);   // transposed store
}

// ---------------- K0: per-PAIR softmax/KL (float2 + batched prefetch) -------
// Round-4 float2 structure (best measured variant, ~31us) with the channel
// loop split into 4 explicit load batches (5/5/5/4 channels). Phase A issues
// all 15 batch loads into statically-indexed register arrays (fully unrolled
// -> registers, not scratch); phase B consumes them in the identical
// c-ascending order (bitwise-unchanged vs rounds 1-5, absmax 0.0 throughout).
// Rationale: round-4 kept only ~1 iteration's loads (~20 B/lane) in flight ->
// 2.5 TB/s effective, latency-bound. One batch puts 100 B/lane = 6.4 KB/wave
// in flight; 12.5 waves/CU saturates the latency*BW product. 4 round-trips
// per thread instead of 19.
__global__ __launch_bounds__(256) void k_soft(const float* __restrict__ sl, const int* __restrict__ tgt,
                                              float* __restrict__ logZ, float* __restrict__ S,
                                              float* __restrict__ kl_map, int* __restrict__ hist,
                                              float* __restrict__ out) {
  int t = blockIdx.x * 256 + threadIdx.x;        // pair index, 0..NPIX_/2-1
  int b = t / (HW_ / 2), q = t - b * (HW_ / 2);
  int p = q * 2;                                 // pixel base (j even)
  int i = p / W_, j = p - i * W_;
  bool hd = (i < H_ - 1);
  bool hr1 = (j + 2 < W_);                       // pixel1 has a right neighbor
  __shared__ float et[NEPS_];
  __shared__ int sh[257];
  et[threadIdx.x] = EPS.v[threadIdx.x];
  sh[threadIdx.x] = 0;
  if (threadIdx.x == 0) sh[256] = 0;

  const float* base = sl + (size_t)b * CHW_ + p;
  int2 t2 = *(const int2*)(tgt + b * HW_ + p);

  float se0=0.f,se1=0.f, E0=0.f,E1=0.f;
  float dD0=0.f,dD1=0.f, sB0=0.f,sB1=0.f;
  float dR0=0.f,dR1=0.f, sR1=0.f;
  float xt0=0.f,xt1=0.f;
  #pragma unroll
  for (int c0 = 0; c0 < C_; c0 += 5) {
    const int NB = (c0 + 5 <= C_) ? 5 : (C_ - c0);
    // ---- phase A: issue the whole batch (independent loads) ----
    float2 xo[5], xd[5];
    float  xr[5];
    #pragma unroll
    for (int k = 0; k < NB; ++k) {
      const float* pc = base + (c0 + k) * HW_;
      xo[k] = *(const float2*)pc;
      xd[k] = hd ? *(const float2*)(pc + W_) : make_float2(0.f, 0.f);
      xr[k] = hr1 ? pc[2] : 0.f;
    }
    // ---- phase B: consume in identical c-ascending order ----
    #pragma unroll
    for (int k = 0; k < NB; ++k) {
      int c = c0 + k;
      float e0 = __expf(xo[k].x), e1 = __expf(xo[k].y);
      se0 += e0; E0 += e0 * xo[k].x;
      se1 += e1; E1 += e1 * xo[k].y;
      dD0 += e0 * xd[k].x; dD1 += e1 * xd[k].y;
      sB0 += __expf(xd[k].x); sB1 += __expf(xd[k].y);
      dR0 += e0 * xo[k].y; dR1 += e1 * xr[k];
      sR1 += __expf(xr[k]);
      if (c == t2.x) xt0 = xo[k].x;
      if (c == t2.y) xt1 = xo[k].y;
    }
  }
  float lz0 = __logf(se0), lz1 = __logf(se1);
  float Sv0 = E0 / se0 - lz0, Sv1 = E1 / se1 - lz1;
  float nll = ((t2.x != IGN_) ? (lz0 - xt0) : 0.f) + ((t2.y != IGN_) ? (lz1 - xt1) : 0.f);
  // kl_tb (0 at last row)
  float kl0 = hd ? (Sv0 - dD0 / se0 + __logf(sB0)) : 0.f;
  float kl1 = hd ? (Sv1 - dD1 / se1 + __logf(sB1)) : 0.f;
  // kl_lr: pixel0's right neighbor is pixel1 (register stats, bitwise = its own)
  kl0 += Sv0 - dR0 / se0 + lz1;
  if (hr1) kl1 += Sv1 - dR1 / se1 + __logf(sR1);
  int gp = b * HW_ + p;
  *(float2*)(logZ + gp)   = make_float2(lz0, lz1);
  *(float2*)(S + gp)      = make_float2(Sv0, Sv1);
  *(float2*)(kl_map + gp) = make_float2(kl0, kl1);
  __syncthreads();                       // et/sh init visible
  atomicAdd(&sh[eps_bin(kl0, et)], 1);
  atomicAdd(&sh[eps_bin(kl1, et)], 1);
  __syncthreads();
  if (sh[threadIdx.x]) atomicAdd(&hist[threadIdx.x], sh[threadIdx.x]);
  if (threadIdx.x == 0 && sh[256]) atomicAdd(&hist[256], sh[256]);
  block_reduce_add_w(nll, out, 4);
}

// ---------------- K2: column combine + (block 0) eps selection --------------
// Reads the TRANSPOSED R: lev[0] load fully coalesced.
__global__ __launch_bounds__(H_) void k_coldt(const int* __restrict__ Rt, int* __restrict__ dist,
                                              const int* __restrict__ hist, float* __restrict__ eps_sel) {
  int b = blockIdx.x / W_, j = blockIdx.x % W_, tid = threadIdx.x;
  __shared__ int lev[9][H_];
  lev[0][tid] = Rt[(b * W_ + j) * H_ + tid];
  int Ri = lev[0][tid];
  for (int l = 1; l <= 8; ++l) {
    int half = 1 << (l - 1);
    __syncthreads();
    int other = (tid + half < H_) ? lev[l - 1][tid + half] : INF_;
    lev[l][tid] = min(lev[l - 1][tid], other);
  }
  __syncthreads();
  int i0 = tid;
  auto feas = [&](int dd) -> bool {
    int lo = max(0, i0 - dd), hi = min(H_ - 1, i0 + dd);
    int len = hi - lo + 1;
    int l = 31 - __clz(len);
    int m = min(lev[l][lo], lev[l][hi - (1 << l) + 1]);
    return m <= dd;
  };
  int d;
  int hi = min(Ri, 512);                 // d <= R[i0]
  if (!feas(hi)) d = B_ + 1 + H_ + W_;   // no seed in image
  else {
    int lo = 0;
    while (lo < hi) { int mid = (lo + hi) >> 1; if (feas(mid)) hi = mid; else lo = mid + 1; }
    d = lo;
  }
  dist[(b * H_ + i0) * W_ + j] = d;
  // block 0: eps via suffix scan of hist (bins 1..256)
  if (blockIdx.x == 0) {
    __shared__ int g[256];
    __shared__ int bestk;
    if (tid < 256) g[tid] = hist[tid + 1];
    if (tid == 0) bestk = NEPS_ - 1;
    __syncthreads();
    #pragma unroll
    for (int ofs = 1; ofs < 256; ofs <<= 1) {
      int v = 0;
      if (tid < 256) v = g[tid] + ((tid + ofs < 256) ? g[tid + ofs] : 0);
      __syncthreads();
      if (tid < 256) g[tid] = v;
      __syncthreads();
    }
    if (tid < 256 && g[tid] <= 5120) atomicMin(&bestk, tid);
    __syncthreads();
    if (tid == 0) eps_sel[0] = EPS.v[bestk];
  }
}

// ---------------- K3: mask+direction+dterm + in-block sparse CE -------------
__global__ __launch_bounds__(256) void k_maskce(const float* __restrict__ sl, const float* __restrict__ logZ,
                                                const float* __restrict__ S, const float* __restrict__ kl_map,
                                                const int* __restrict__ dist, const float* __restrict__ eps_sel,
                                                float* __restrict__ out) {
  const int nx9[9] = {1,-1,0,0,-1,1,-1,1,0};
  const int ny9[9] = {0,0,-1,1,1,1,-1,-1,0};
  int tid = threadIdx.x;
  int b = blockIdx.z;
  int i0 = blockIdx.y * 16, j0 = blockIdx.x * 16;
  float eps = eps_sel[0];
  __shared__ float kt[18][19];
  __shared__ int   dt_[18][19];
  for (int e = tid; e < 324; e += 256) {
    int r = e / 18, cc = e - r * 18;
    int gi = i0 - 1 + r, gj = j0 - 1 + cc;
    bool in = (gi >= 0 && gi < H_ && gj >= 0 && gj < W_);
    int gidx = (b * H_ + gi) * W_ + gj;
    kt[r][cc]  = in ? kl_map[gidx] : -1e30f;
    dt_[r][cc] = in ? dist[gidx] : 100000;
  }
  __syncthreads();
  int li = tid >> 4, lj = tid & 15;
  bool mask = false;
  #pragma unroll
  for (int dr = 0; dr < 3; ++dr)
    #pragma unroll
    for (int dc = 0; dc < 3; ++dc)
      mask |= (kt[li + dr][lj + dc] > eps);
  int best = INF_, dir = 0;
  #pragma unroll
  for (int k = 0; k < 9; ++k) {
    int r = dt_[li + 1 + nx9[k]][lj + 1 + ny9[k]];
    if (r < best) { best = r; dir = k; }
  }
  bool valid = mask && (dir != 8);
  float acc = valid ? fminf((float)dt_[li + 1][lj + 1], 20.f) * (1.f / 20.f) : 0.f;
  // compact valid pixels into LDS list
  __shared__ int list_[256];
  __shared__ int woff[4];
  __shared__ int tot_s;
  int lane = tid & 63, wid = tid >> 6;
  unsigned long long vote = __ballot(valid);
  if (lane == 0) woff[wid] = __popcll(vote);
  __syncthreads();
  if (tid == 0) {
    int c0 = woff[0], c1 = woff[1], c2 = woff[2], c3 = woff[3];
    tot_s = c0 + c1 + c2 + c3;
    woff[0] = 0; woff[1] = c0; woff[2] = c0 + c1; woff[3] = c0 + c1 + c2;
  }
  __syncthreads();
  if (valid)
    list_[woff[wid] + __popcll(vote & ((1ULL << lane) - 1ULL))] = tid | (min(dir, 7) << 8);
  __syncthreads();
  int cnt = tot_s;
  const float* bse = sl + (size_t)b * CHW_;
  // CE: 8 lanes per entry (lane k = neighbor k)
  for (int base0 = 0; base0 < cnt; base0 += 32) {
    int e = base0 + (tid >> 3), k = tid & 7;
    float ce = 0.f;
    if (e < cnt) {
      int w = list_[e];
      int label = w >> 8, lpos = w & 255;
      int i = i0 + (lpos >> 4), j = j0 + (lpos & 15);
      int pix = i * W_ + j;
      float lzc = logZ[b * HW_ + pix];
      int ic = min(max(i + nx9[k], 0), H_ - 1);
      int jc = min(max(j + ny9[k], 0), W_ - 1);
      int npx = ic * W_ + jc;
      float lzn = logZ[b * HW_ + npx], Sn = S[b * HW_ + npx];
      float dot = 0.f;
      #pragma unroll
      for (int c = 0; c < C_; ++c)
        dot += __expf(bse[c * HW_ + npx] - lzn) * bse[c * HW_ + pix];
      float kv = Sn - dot + lzc;
      float kmax = kv;
      #pragma unroll
      for (int o = 1; o < 8; o <<= 1) kmax = fmaxf(kmax, __shfl_xor(kmax, o));
      float ssum = __expf(kv - kmax);
      #pragma unroll
      for (int o = 1; o < 8; o <<= 1) ssum += __shfl_xor(ssum, o);
      float kll = __shfl(kv, (lane & ~7) | label);
      if (k == 0) ce = kmax + __logf(ssum) - kll;
    }
    acc += ce;
  }
  block_reduce_add_w(acc, out, 4);
}

// ---------------- launch -----------------------------------------------------
extern "C" void kernel_launch(void* const* d_in, const int* in_sizes, int n_in,
                              void* d_out, int out_size, void* d_ws, size_t ws_size,
                              hipStream_t stream) {
  const float* sl  = (const float*)d_in[0];
  const int*   tgt = (const int*)d_in[1];
  float* out = (float*)d_out;

  int*   hist    = (int*)d_ws;                 // 257 ints (zeroed by k_rowdt)
  float* eps_sel = (float*)d_ws + 320;
  float* logZ    = (float*)d_ws + 512;
  float* S       = logZ + NPIX_;
  float* kl_map  = S + NPIX_;
  int*   dist    = (int*)(kl_map + NPIX_);
  int*   Rt      = dist + NPIX_;

  k_rowdt<<<B_ * H_, W_, 0, stream>>>(tgt, Rt, hist, out);
  k_soft<<<NPIX_ / 2 / 256, 256, 0, stream>>>(sl, tgt, logZ, S, kl_map, hist, out);
  k_coldt<<<B_ * W_, H_, 0, stream>>>(Rt, dist, hist, eps_sel);
  k_maskce<<<dim3(W_ / 16, H_ / 16, B_), 256, 0, stream>>>(sl, logZ, S, kl_map, dist, eps_sel, out);
}